// Round 4
// baseline (4047.160 us; speedup 1.0000x reference)
//
#include <hip/hip_runtime.h>

#define N_NODES 100000
#define N_EDGES 1600000
#define N_GRAPHS 1024
#define HID 128
#define LAYERS 4
#define LN_EPS 1e-5f
#define LPAD (HID + 4)
#define NB_SCAN 391  // ceil(100000/256)

// ---------------- input projection: h = x @ inW + inb ----------------
__global__ __launch_bounds__(256) void k_input_proj(
    const float* __restrict__ x, const float* __restrict__ inW,
    const float* __restrict__ inb, float* __restrict__ h) {
    int idx = blockIdx.x * 256 + threadIdx.x;  // over N_NODES*HID (exact)
    int n = idx >> 7, c = idx & 127;
    const float* xr = x + n * 7;
    float s = inb[c];
#pragma unroll
    for (int k = 0; k < 7; ++k) s += xr[k] * inW[k * HID + c];
    h[idx] = s;
}

// ---------------- CSR build: histogram of dst ------------------------
__global__ __launch_bounds__(256) void k_hist(
    const int* __restrict__ ei, int* __restrict__ deg) {
    int e = blockIdx.x * 256 + threadIdx.x;  // N_EDGES exact
    atomicAdd(&deg[ei[N_EDGES + e]], 1);
}

// ---------------- CSR build: parallel 3-stage scan -------------------
__global__ __launch_bounds__(256) void k_scan1(
    const int* __restrict__ deg, int* __restrict__ bsum) {
    const int i = blockIdx.x * 256 + threadIdx.x;
    int v = (i < N_NODES) ? deg[i] : 0;
#pragma unroll
    for (int off = 1; off < 64; off <<= 1) v += __shfl_xor(v, off);
    __shared__ int wsum[4];
    if ((threadIdx.x & 63) == 0) wsum[threadIdx.x >> 6] = v;
    __syncthreads();
    if (threadIdx.x == 0) bsum[blockIdx.x] = wsum[0] + wsum[1] + wsum[2] + wsum[3];
}

__global__ __launch_bounds__(512) void k_scan2(
    const int* __restrict__ bsum, int* __restrict__ bpre) {
    __shared__ int tmp[512];
    const int t = threadIdx.x;
    int v = (t < NB_SCAN) ? bsum[t] : 0;
    tmp[t] = v;
    __syncthreads();
    for (int off = 1; off < 512; off <<= 1) {
        int u = (t >= off) ? tmp[t - off] : 0;
        __syncthreads();
        tmp[t] += u;
        __syncthreads();
    }
    if (t < NB_SCAN) bpre[t] = tmp[t] - v;  // exclusive
}

__global__ __launch_bounds__(256) void k_scan3(
    const int* __restrict__ deg, const int* __restrict__ bpre,
    int* __restrict__ row_ptr, int* __restrict__ cursor) {
    __shared__ int tmp[256];
    const int t = threadIdx.x;
    const int i = blockIdx.x * 256 + t;
    int d = (i < N_NODES) ? deg[i] : 0;
    tmp[t] = d;
    __syncthreads();
    for (int off = 1; off < 256; off <<= 1) {
        int u = (t >= off) ? tmp[t - off] : 0;
        __syncthreads();
        tmp[t] += u;
        __syncthreads();
    }
    if (i < N_NODES) {
        const int ex = bpre[blockIdx.x] + tmp[t] - d;
        row_ptr[i] = ex;
        cursor[i] = ex;
        if (i == N_NODES - 1) row_ptr[N_NODES] = N_EDGES;
    }
}

// ---------------- CSR build: scatter edges into sorted slots ---------
__global__ __launch_bounds__(256) void k_scatter(
    const int* __restrict__ ei, const float* __restrict__ ea,
    int* __restrict__ cursor, float4* __restrict__ edata) {
    int e = blockIdx.x * 256 + threadIdx.x;  // N_EDGES exact
    const int src = ei[e];
    const int dst = ei[N_EDGES + e];
    const int pos = atomicAdd(&cursor[dst], 1);
    edata[pos] = make_float4(ea[e * 3 + 0], ea[e * 3 + 1], ea[e * 3 + 2],
                             __int_as_float(src));
}

// ------- fused gather-aggregate + MLP + residual + layernorm ---------
// 256 threads = 4 waves; each wave owns 4 nodes end-to-end. The wave's 4
// CSR rows are contiguous -> one merged edge stream, software-pipelined
// with a register double buffer (edata loads for group i+1 overlap the
// h-row gathers of group i). No __syncthreads anywhere.
__global__ __launch_bounds__(256) void k_node_update(
    const float4* __restrict__ edata, const int* __restrict__ row_ptr,
    const float* __restrict__ eW, const float* __restrict__ eb,
    const float* __restrict__ hin, float* __restrict__ hout,
    const float* __restrict__ w1, const float* __restrict__ b1,
    const float* __restrict__ w2, const float* __restrict__ b2,
    const float* __restrict__ gamma, const float* __restrict__ beta) {
    __shared__ float gt[16][LPAD];
    __shared__ float t1[16][LPAD];
    const int wave = threadIdx.x >> 6;
    const int lane = threadIdx.x & 63;
    const int c2 = lane * 2;            // this thread's 2 columns
    const int n0 = blockIdx.x * 16;
    const int r0 = wave * 4;            // this wave's first row slot

    // ---- phase 1: merged-stream gather-aggregate ----
    {
        const float2 ew0 = *(const float2*)(eW + 0 * HID + c2);
        const float2 ew1 = *(const float2*)(eW + 1 * HID + c2);
        const float2 ew2 = *(const float2*)(eW + 2 * HID + c2);
        const float2 ebv = *(const float2*)(eb + c2);
        const int nb = n0 + r0;
        const int rp0 = row_ptr[nb + 0];
        const int rp1 = row_ptr[nb + 1];
        const int rp2 = row_ptr[nb + 2];
        const int rp3 = row_ptr[nb + 3];
        const int rp4 = row_ptr[nb + 4];

        float a0x, a0y, a1x, a1y, a2x, a2y, a3x, a3y;
        { const float2 v = *(const float2*)(hin + (long)(nb + 0) * HID + c2); a0x = v.x; a0y = v.y; }
        { const float2 v = *(const float2*)(hin + (long)(nb + 1) * HID + c2); a1x = v.x; a1y = v.y; }
        { const float2 v = *(const float2*)(hin + (long)(nb + 2) * HID + c2); a2x = v.x; a2y = v.y; }
        { const float2 v = *(const float2*)(hin + (long)(nb + 3) * HID + c2); a3x = v.x; a3y = v.y; }

        auto acc1 = [&](const float4& ed, const float2& g, int idx) {
            const float mx = fmaxf(g.x + ed.x * ew0.x + ed.y * ew1.x + ed.z * ew2.x + ebv.x, 0.f);
            const float my = fmaxf(g.y + ed.x * ew0.y + ed.y * ew1.y + ed.z * ew2.y + ebv.y, 0.f);
            if (idx < rp1)      { a0x += mx; a0y += my; }
            else if (idx < rp2) { a1x += mx; a1y += my; }
            else if (idx < rp3) { a2x += mx; a2y += my; }
            else                { a3x += mx; a3y += my; }
        };
        auto proc4 = [&](const float4* B4, int ebase) {
            const int s0_ = __builtin_amdgcn_readfirstlane(__float_as_int(B4[0].w));
            const int s1_ = __builtin_amdgcn_readfirstlane(__float_as_int(B4[1].w));
            const int s2_ = __builtin_amdgcn_readfirstlane(__float_as_int(B4[2].w));
            const int s3_ = __builtin_amdgcn_readfirstlane(__float_as_int(B4[3].w));
            const float2 g0 = *(const float2*)(hin + (long)s0_ * HID + c2);
            const float2 g1 = *(const float2*)(hin + (long)s1_ * HID + c2);
            const float2 g2 = *(const float2*)(hin + (long)s2_ * HID + c2);
            const float2 g3 = *(const float2*)(hin + (long)s3_ * HID + c2);
            acc1(B4[0], g0, ebase + 0);
            acc1(B4[1], g1, ebase + 1);
            acc1(B4[2], g2, ebase + 2);
            acc1(B4[3], g3, ebase + 3);
        };

        float4 A[4], B[4];
        int e = rp0;
        int rem = rp4 - rp0;
        if (rem >= 4) { A[0] = edata[e]; A[1] = edata[e + 1]; A[2] = edata[e + 2]; A[3] = edata[e + 3]; }
        while (rem >= 12) {
            B[0] = edata[e + 4]; B[1] = edata[e + 5]; B[2] = edata[e + 6]; B[3] = edata[e + 7];
            proc4(A, e);
            A[0] = edata[e + 8]; A[1] = edata[e + 9]; A[2] = edata[e + 10]; A[3] = edata[e + 11];
            proc4(B, e + 4);
            e += 8; rem -= 8;
        }
        if (rem >= 8) {
            B[0] = edata[e + 4]; B[1] = edata[e + 5]; B[2] = edata[e + 6]; B[3] = edata[e + 7];
            proc4(A, e);
            proc4(B, e + 4);
            e += 8; rem -= 8;
        } else if (rem >= 4) {
            proc4(A, e);
            e += 4; rem -= 4;
        }
        for (; rem > 0; --rem, ++e) {
            const float4 ed = edata[e];
            const int sr = __builtin_amdgcn_readfirstlane(__float_as_int(ed.w));
            const float2 gv = *(const float2*)(hin + (long)sr * HID + c2);
            acc1(ed, gv, e);
        }
        *(float2*)&gt[r0 + 0][c2] = make_float2(a0x, a0y);
        *(float2*)&gt[r0 + 1][c2] = make_float2(a1x, a1y);
        *(float2*)&gt[r0 + 2][c2] = make_float2(a2x, a2y);
        *(float2*)&gt[r0 + 3][c2] = make_float2(a3x, a3y);
    }
    // same-wave LDS producer/consumer: hardware-ordered, no barrier needed

    // ---- phase 2: t1 = relu(gt @ w1 + b1), b128 4-k blocking ----
    {
        float acc[4][2];
        const float2 bv = *(const float2*)(b1 + c2);
#pragma unroll
        for (int r = 0; r < 4; ++r) { acc[r][0] = bv.x; acc[r][1] = bv.y; }
        for (int k4 = 0; k4 < HID; k4 += 4) {
            float4 g4[4];
#pragma unroll
            for (int r = 0; r < 4; ++r) g4[r] = *(const float4*)&gt[r0 + r][k4];
#pragma unroll
            for (int kk = 0; kk < 4; ++kk) {
                const float2 w = *(const float2*)(w1 + (k4 + kk) * HID + c2);
#pragma unroll
                for (int r = 0; r < 4; ++r) {
                    const float gv = ((const float*)&g4[r])[kk];
                    acc[r][0] += gv * w.x;
                    acc[r][1] += gv * w.y;
                }
            }
        }
#pragma unroll
        for (int r = 0; r < 4; ++r) {
            *(float2*)&t1[r0 + r][c2] =
                make_float2(fmaxf(acc[r][0], 0.f), fmaxf(acc[r][1], 0.f));
        }
    }

    // ---- phase 3: u = hin + relu(t1 @ w2 + b2); fused layernorm ----
    {
        float acc[4][2];
        const float2 bv = *(const float2*)(b2 + c2);
#pragma unroll
        for (int r = 0; r < 4; ++r) { acc[r][0] = bv.x; acc[r][1] = bv.y; }
        for (int k4 = 0; k4 < HID; k4 += 4) {
            float4 t4[4];
#pragma unroll
            for (int r = 0; r < 4; ++r) t4[r] = *(const float4*)&t1[r0 + r][k4];
#pragma unroll
            for (int kk = 0; kk < 4; ++kk) {
                const float2 w = *(const float2*)(w2 + (k4 + kk) * HID + c2);
#pragma unroll
                for (int r = 0; r < 4; ++r) {
                    const float tv = ((const float*)&t4[r])[kk];
                    acc[r][0] += tv * w.x;
                    acc[r][1] += tv * w.y;
                }
            }
        }
        const float2 gmv = *(const float2*)(gamma + c2);
        const float2 btv = *(const float2*)(beta + c2);
#pragma unroll
        for (int r = 0; r < 4; ++r) {
            const int n = n0 + r0 + r;
            const float2 hv = *(const float2*)(hin + (long)n * HID + c2);
            const float ux = hv.x + fmaxf(acc[r][0], 0.f);
            const float uy = hv.y + fmaxf(acc[r][1], 0.f);
            float s = ux + uy, s2 = ux * ux + uy * uy;
#pragma unroll
            for (int off = 1; off < 64; off <<= 1) {
                s += __shfl_xor(s, off);
                s2 += __shfl_xor(s2, off);
            }
            const float mu = s * (1.f / HID);
            const float var = s2 * (1.f / HID) - mu * mu;
            const float inv = rsqrtf(var + LN_EPS);
            float2 o;
            o.x = (ux - mu) * inv * gmv.x + btv.x;
            o.y = (uy - mu) * inv * gmv.y + btv.y;
            *(float2*)(hout + (long)n * HID + c2) = o;
        }
    }
}

// -------- global mean pool: segmented reduction (batch is sorted) ----
__global__ __launch_bounds__(128) void k_pool(
    const float* __restrict__ h, const int* __restrict__ batch,
    float* __restrict__ sums, float* __restrict__ cnt) {
    const int c = threadIdx.x;
    const int n0 = blockIdx.x * 128;
    if (n0 >= N_NODES) return;
    const int nend = min(n0 + 128, N_NODES);
    int cur = batch[n0];
    float acc = 0.f;
    int runlen = 0;
    for (int n = n0; n < nend; ++n) {
        const int b = batch[n];
        if (b != cur) {
            atomicAdd(&sums[(long)cur * HID + c], acc);
            if (c == 0) atomicAdd(&cnt[cur], (float)runlen);
            acc = 0.f;
            runlen = 0;
            cur = b;
        }
        acc += h[(long)n * HID + c];
        ++runlen;
    }
    atomicAdd(&sums[(long)cur * HID + c], acc);
    if (c == 0) atomicAdd(&cnt[cur], (float)runlen);
}

// ---------------- head: 1 block per graph ----------------------------
__global__ __launch_bounds__(128) void k_head(
    const float* __restrict__ sums, const float* __restrict__ cnt,
    const float* __restrict__ fcW1, const float* __restrict__ fcb1,
    const float* __restrict__ fcW2, const float* __restrict__ fcb2,
    const float* __restrict__ fcW3, const float* __restrict__ fcb3,
    float* __restrict__ out) {
    __shared__ float p[HID];
    __shared__ float o1[HID];
    __shared__ float o2[64];
    const int g = blockIdx.x, t = threadIdx.x;
    const float c = fmaxf(cnt[g], 1.0f);
    p[t] = sums[g * HID + t] / c;
    __syncthreads();
    float s = fcb1[t];
    for (int k = 0; k < HID; ++k) s += p[k] * fcW1[k * HID + t];
    o1[t] = fmaxf(s, 0.f);
    __syncthreads();
    if (t < 64) {
        float s2 = fcb2[t];
        for (int k = 0; k < HID; ++k) s2 += o1[k] * fcW2[k * 64 + t];
        o2[t] = fmaxf(s2, 0.f);
    }
    __syncthreads();
    if (t < 64) {
        float v = o2[t] * fcW3[t];
#pragma unroll
        for (int off = 32; off > 0; off >>= 1) v += __shfl_down(v, off);
        if (t == 0) out[g] = v + fcb3[0];
    }
}

extern "C" void kernel_launch(void* const* d_in, const int* in_sizes, int n_in,
                              void* d_out, int out_size, void* d_ws, size_t ws_size,
                              hipStream_t stream) {
    const float* x    = (const float*)d_in[0];
    const int*   ei   = (const int*)d_in[1];
    const float* ea   = (const float*)d_in[2];
    const int*   batch= (const int*)d_in[3];
    const float* inW  = (const float*)d_in[4];
    const float* inb  = (const float*)d_in[5];
    const float* edgeW= (const float*)d_in[6];
    const float* edgeb= (const float*)d_in[7];
    const float* w1   = (const float*)d_in[8];
    const float* b1   = (const float*)d_in[9];
    const float* w2   = (const float*)d_in[10];
    const float* b2   = (const float*)d_in[11];
    const float* gamma= (const float*)d_in[12];
    const float* beta = (const float*)d_in[13];
    const float* fcW1 = (const float*)d_in[14];
    const float* fcb1 = (const float*)d_in[15];
    const float* fcW2 = (const float*)d_in[16];
    const float* fcb2 = (const float*)d_in[17];
    const float* fcW3 = (const float*)d_in[18];
    const float* fcb3 = (const float*)d_in[19];
    float* out = (float*)d_out;

    // workspace layout (float4-aligned first)
    float4* edata  = (float4*)d_ws;                               // 1.6M float4
    float*  h0     = (float*)(edata + N_EDGES);                   // 12.8M f32
    float*  h1     = h0 + (size_t)N_NODES * HID;                  // 12.8M f32
    int*    row_ptr= (int*)(h1 + (size_t)N_NODES * HID);          // 100001
    int*    cursor = row_ptr + (N_NODES + 1);                     // 100000
    int*    deg    = cursor + N_NODES;                            // 100000
    int*    bsum   = deg + N_NODES;                               // 392
    int*    bpre   = bsum + 512;                                  // 392
    float*  sums   = (float*)(bpre + 512);                        // 1024*128
    float*  cnt    = sums + (size_t)N_GRAPHS * HID;               // 1024

    hipMemsetAsync(deg, 0, N_NODES * sizeof(int), stream);
    hipMemsetAsync(sums, 0, ((size_t)N_GRAPHS * HID + N_GRAPHS) * sizeof(float), stream);

    k_input_proj<<<(N_NODES * HID) / 256, 256, 0, stream>>>(x, inW, inb, h0);

    // CSR build (once per launch, reused across 4 layers)
    k_hist<<<N_EDGES / 256, 256, 0, stream>>>(ei, deg);
    k_scan1<<<NB_SCAN, 256, 0, stream>>>(deg, bsum);
    k_scan2<<<1, 512, 0, stream>>>(bsum, bpre);
    k_scan3<<<NB_SCAN, 256, 0, stream>>>(deg, bpre, row_ptr, cursor);
    k_scatter<<<N_EDGES / 256, 256, 0, stream>>>(ei, ea, cursor, edata);

    float* hin = h0;
    float* hout = h1;
    for (int l = 0; l < LAYERS; ++l) {
        k_node_update<<<N_NODES / 16, 256, 0, stream>>>(
            edata, row_ptr, edgeW + l * 3 * HID, edgeb + l * HID, hin, hout,
            w1 + l * HID * HID, b1 + l * HID, w2 + l * HID * HID, b2 + l * HID,
            gamma + l * HID, beta + l * HID);
        float* tmp = hin; hin = hout; hout = tmp;
    }
    // after 4 swaps, final h is back in h0 (== hin)

    k_pool<<<(N_NODES + 127) / 128, 128, 0, stream>>>(hin, batch, sums, cnt);
    k_head<<<N_GRAPHS, 128, 0, stream>>>(sums, cnt, fcW1, fcb1, fcW2, fcb2,
                                         fcW3, fcb3, out);
}